// Round 11
// baseline (166.839 us; speedup 1.0000x reference)
//
#include <hip/hip_runtime.h>
#include <hip/hip_bf16.h>

// B=4, S=2048, D=1024. x:[4,2048,1024] f32; wq/wk/wv:[1024,1024] f32.
// out:[4,2048,1024] f32.
//
// R11 pipeline (identical dispatch plan to R10; GEMM core changed):
//   scores = x (Wq Wk^T/32) x^T  (Mt precomputed; K-proj eliminated)
//   1. convall: x,wq,wk -> bf16
//   2. wtrans:  wv -> wtv bf16 transposed
//   3. gemm128<5>: Mt = (wkb @ wqb^T)/32        [1024x1024] bf16
//   4. gemm128<5>: t  = xb @ Mt^T               [8192x1024] bf16
//   5. gemm128<1>: MERGED: 544 live-triangular scores (bf16) + 512 VT
//   6. softmax_wave: row-per-wave register softmax, bf16 in-place
//   7. gemm128<2>: out = attn @ vt^T, paired heavy/light blocks
//
// R11 GEMM core (T4 counted-vmcnt, 2-deep prefetch):
//   BK=32, 3-buffer LDS ring As[3][128][32]+Bs[3][128][32] = 48 KiB
//   -> 3 blocks/CU. Staging runs 2 K-tiles ahead (4 gloads/tile);
//   steady-state wait is vmcnt(8): tile t's 4 loads (issued 2 compute
//   phases ~2 step-times earlier) landed; tiles t+1,t+2 (8 loads) stay in
//   flight ACROSS the barrier — never drained mid-loop (T4). Ring safety:
//   stage(t+2) overwrites buf[(t-1)%3]; all reads of t-1 retired before
//   iter t-1's closing barrier, which precedes iter t's stage. Waits:
//   12->vmcnt(8) steady, 8->vmcnt(4), 4->vmcnt(0) (peeled tail).
//   Swizzle (both-sides, 2-way-free): 64-B rows; reader phys 16B-slot =
//   g ^ ((row>>1)&3); writer pre-swizzles source: sl=(tid&3)^((tid>>3)&3).

typedef __attribute__((ext_vector_type(8))) short bf16x8;
typedef __attribute__((ext_vector_type(4))) float f32x4;

#define GLOAD_LDS16(g, l)                                                     \
    __builtin_amdgcn_global_load_lds(                                         \
        (const __attribute__((address_space(1))) void*)(g),                   \
        (__attribute__((address_space(3))) void*)(l), 16, 0, 0)

__device__ __forceinline__ short f2bf(float f) {
    union { float f; unsigned u; } v; v.f = f;
    unsigned r = v.u + 0x7FFFu + ((v.u >> 16) & 1u);
    return (short)(r >> 16);
}
__device__ __forceinline__ float bf2f(short h) {
    union { unsigned u; float f; } v;
    v.u = ((unsigned)(unsigned short)h) << 16;
    return v.f;
}

// ------- fused f32->bf16 converts: x (2M f4), wq (256K f4), wk (256K f4) ----
__global__ __launch_bounds__(256) void convall(
    const float* __restrict__ x, const float* __restrict__ wq,
    const float* __restrict__ wk, short* __restrict__ xb,
    short* __restrict__ wqb, short* __restrict__ wkb) {
    int i = blockIdx.x * 256 + threadIdx.x;  // grid 2048
#pragma unroll
    for (int s = 0; s < 5; ++s) {
        int v = i + s * 524288;              // < 2621440
        const float* src;
        short* dst;
        int off;
        if (v < 2097152)      { src = x;  dst = xb;  off = v; }
        else if (v < 2359296) { src = wq; dst = wqb; off = v - 2097152; }
        else                  { src = wk; dst = wkb; off = v - 2359296; }
        float4 w = ((const float4*)src)[off];
        short4 o;
        o.x = f2bf(w.x); o.y = f2bf(w.y); o.z = f2bf(w.z); o.w = f2bf(w.w);
        ((short4*)dst)[off] = o;
    }
}

// ---------------- wv: f32 [k][n] -> bf16 [n][k] ----------------
__global__ __launch_bounds__(256) void wtrans(const float* __restrict__ W,
                                              short* __restrict__ O) {
    int n0 = blockIdx.x * 64, k0 = blockIdx.y * 64;
    __shared__ float tile[64][65];
    int t = threadIdx.x;
#pragma unroll
    for (int i = 0; i < 16; ++i) {
        int idx = t + i * 256;
        int r = idx >> 6, c = idx & 63;
        tile[r][c] = W[(size_t)(k0 + r) * 1024 + n0 + c];
    }
    __syncthreads();
#pragma unroll
    for (int i = 0; i < 16; ++i) {
        int idx = t + i * 256;
        int r = idx >> 6, c = idx & 63;
        O[(size_t)(n0 + r) * 1024 + k0 + c] = f2bf(tile[c][r]);
    }
}

// ------- 128x128 NT GEMM, BK=32, 3-buffer ring, counted vmcnt -------
// C[m][n] = sum_k A[m][k] * B[n][k]
// MODE 5: plain bf16 out (ld 1024), *scale
// MODE 1: merged, grid 1056: bid<544 scores (triangular, causal, bf16 out
//         ld 2048); bid>=544 VT (bf16 out [4][1024][2048])
// MODE 2: PV, grid 512, paired heavy/light decode; A bf16 lda=2048
template <int MODE>
__global__ __launch_bounds__(256, 3) void gemm128(
    const short* __restrict__ A0, int lda0, long long sA,
    const short* __restrict__ B0, int ldb0, long long sB,
    void* __restrict__ C0, float scale,
    const short* __restrict__ Av, const short* __restrict__ Bv,
    short* __restrict__ Cv) {

    int m0, n0, z = 0, lda = lda0, ldb = ldb0;
    const short* Ab;
    const short* Bb;
    bool isVT = false;

    if (MODE == 2) {
        // paired decode: slots i and i+256 carry mt and 15-mt (sum const)
        int i = blockIdx.x;            // 0..511
        int j = i & 255;
        int mt = (i < 256) ? (15 - (j >> 5)) : (j >> 5);
        z = (j >> 3) & 3;
        m0 = mt * 128;
        n0 = (j & 7) * 128;
        Ab = A0 + (size_t)z * sA;
        Bb = B0 + (size_t)z * sB;
    } else {
        // T1: XCD swizzle (grids are multiples of 8)
        const int nblk = gridDim.x;
        const int raw = blockIdx.x;
        int bid = (raw & 7) * (nblk >> 3) + (raw >> 3);
        if (MODE == 5) {
            m0 = (bid >> 3) * 128;
            n0 = (bid & 7) * 128;
            Ab = A0; Bb = B0;
        } else {  // MODE 1
            if (bid < 544) {
                z = bid / 136;
                int f = bid - z * 136;
                int mt = (int)((sqrtf(8.f * f + 1.f) - 1.f) * 0.5f);
                if (mt * (mt + 1) / 2 > f) --mt;
                if ((mt + 1) * (mt + 2) / 2 <= f) ++mt;
                int nt_ = f - mt * (mt + 1) / 2;   // nt_ <= mt (live)
                m0 = mt * 128; n0 = nt_ * 128;
                Ab = A0 + (size_t)z * sA;
                Bb = B0 + (size_t)z * sB;
            } else {
                isVT = true;
                int v = bid - 544;            // 0..511
                m0 = (v >> 6) * 128;          // M=1024
                n0 = (v & 63) * 128;          // N=8192
                Ab = Av; Bb = Bv; lda = 1024; ldb = 1024;
            }
        }
    }

    const int tid = threadIdx.x;
    const int lane = tid & 63;
    const int wid = tid >> 6;
    const int wm = wid >> 1, wn = wid & 1;  // 2x2 waves, wave tile 64x64

    // 3-buffer ring: [buf][128 rows x 32 shorts] = 8 KiB per matrix-buf
    __shared__ __align__(16) short As[3][4096];
    __shared__ __align__(16) short Bs[3][4096];

    f32x4 acc[4][4] = {};

    const int Kend = (MODE == 2) ? (m0 + 128) : 1024;
    const int nt = Kend >> 5;   // BK=32: MODE0/1/5 -> 32; PV 4..64

    // staging: 4 thr/row x 16B (row = 64 B), 2 issues per matrix (+64 rows).
    // writer pre-swizzle: phys slot (tid&3) holds logical (tid&3)^((row>>1)&3)
    // = (tid&3)^((tid>>3)&3); invariant under row+64.
    const int srow = tid >> 2;                  // 0..63
    const int sl = (tid & 3) ^ ((tid >> 3) & 3);
    const short* Agp = Ab + (size_t)(m0 + srow) * lda + sl * 8;
    const short* Bgp = Bb + (size_t)(n0 + srow) * ldb + sl * 8;

#define SA(kt, bf)                                                            \
    do {                                                                      \
        const int _k = (kt) << 5;                                             \
        GLOAD_LDS16(Agp + _k,                    &As[bf][tid * 8]);           \
        GLOAD_LDS16(Agp + _k + (size_t)64 * lda, &As[bf][2048 + tid * 8]);    \
    } while (0)
#define SB(kt, bf)                                                            \
    do {                                                                      \
        const int _k = (kt) << 5;                                             \
        GLOAD_LDS16(Bgp + _k,                    &Bs[bf][tid * 8]);           \
        GLOAD_LDS16(Bgp + _k + (size_t)64 * ldb, &Bs[bf][2048 + tid * 8]);    \
    } while (0)

    const int r = lane & 15;
    const int g = lane >> 4;   // logical 16B slot (k-chunk) 0..3

#define LDA4(dst, bf)                                                         \
    _Pragma("unroll") for (int q = 0; q < 4; ++q) {                           \
        const int rr = wm * 64 + q * 16 + r;                                  \
        dst[q] = *(const bf16x8*)&As[bf][rr * 32 +                            \
                                         ((g ^ ((rr >> 1) & 3))) * 8];        \
    }
#define LDB4(dst, bf)                                                         \
    _Pragma("unroll") for (int q = 0; q < 4; ++q) {                           \
        const int rb = wn * 64 + q * 16 + r;                                  \
        dst[q] = *(const bf16x8*)&Bs[bf][rb * 32 +                            \
                                         ((g ^ ((rb >> 1) & 3))) * 8];        \
    }
#define LGKM0()                                                               \
    asm volatile("s_waitcnt lgkmcnt(0)" ::: "memory");                        \
    __builtin_amdgcn_sched_barrier(0)
#define VMC(n) asm volatile("s_waitcnt vmcnt(" #n ")" ::: "memory")
#define BAR() __builtin_amdgcn_s_barrier()
#define MF(ar, br)                                                            \
    _Pragma("unroll") for (int mi = 0; mi < 4; ++mi)                          \
        _Pragma("unroll") for (int ni = 0; ni < 4; ++ni)                      \
            acc[mi][ni] = __builtin_amdgcn_mfma_f32_16x16x32_bf16(            \
                ar[mi], br[ni], acc[mi][ni], 0, 0, 0);

    // prologue: stage tiles 0 and 1 into bufs 0,1 (8 loads in flight)
    SA(0, 0); SB(0, 0);
    SA(1, 1); SB(1, 1);

    int bf = 0;   // buffer holding tile t
    int bs = 2;   // buffer to stage tile t+2 into
    for (int t = 0; t < nt; ++t) {
        bf16x8 a[4], b[4];
        if (t + 2 < nt) {
            SA(t + 2, bs); SB(t + 2, bs);
            // outstanding: t(4) + t+1(4) + t+2(4) = 12 -> wait tile t only
            VMC(8);
        } else if (t + 1 < nt) {
            // outstanding: t(4) + t+1(4) = 8 -> wait tile t only
            VMC(4);
        } else {
            VMC(0);
        }
        BAR();   // tile t visible to all waves; prior reads (t-1) retired
        LDA4(a, bf); LDB4(b, bf);
        LGKM0();
        MF(a, b);
        BAR();   // all waves done reading buf bf before it is restaged
        bf = (bf == 2) ? 0 : bf + 1;
        bs = (bs == 2) ? 0 : bs + 1;
    }

    // ---- C epilogue: C/D layout col=lane&15, row=(lane>>4)*4+reg
    const int r4 = (lane >> 4) * 4;
#pragma unroll
    for (int mi = 0; mi < 4; ++mi) {
#pragma unroll
        for (int ni = 0; ni < 4; ++ni) {
            int col = n0 + wn * 64 + ni * 16 + r;
#pragma unroll
            for (int i = 0; i < 4; ++i) {
                int rr = m0 + wm * 64 + mi * 16 + r4 + i;
                float v = acc[mi][ni][i];
                if (MODE == 5) {
                    ((short*)C0)[(size_t)rr * 1024 + col] = f2bf(v * scale);
                } else if (MODE == 1) {
                    if (isVT) {
                        Cv[(size_t)(col >> 11) * 2097152 +
                           (size_t)rr * 2048 + (col & 2047)] = f2bf(v);
                    } else if (col <= rr) {
                        ((short*)C0)[(size_t)z * 4194304 +
                                     (size_t)rr * 2048 + col] = f2bf(v);
                    }
                } else {
                    ((float*)C0)[(size_t)z * 2097152 +
                                 (size_t)rr * 1024 + col] = v;
                }
            }
        }
    }
#undef SA
#undef SB
#undef LDA4
#undef LDB4
#undef LGKM0
#undef VMC
#undef BAR
#undef MF
}

// ------- causal softmax, row per wave, all-register, bf16 in/out -----------
__global__ __launch_bounds__(256) void softmax_wave(short* __restrict__ scores) {
    int row = (blockIdx.x << 2) + (threadIdx.x >> 6);  // 0..8191
    int lane = threadIdx.x & 63;
    int b = row >> 11, i = row & 2047;
    short* srow = scores + ((size_t)(b << 11) + i) * 2048;
    int L = i + 1;
    int Lpad = (i | 127) + 1;   // PV read extent for this row's block

    float vals[32];
    float mx = -1e30f;
#pragma unroll
    for (int s = 0; s < 4; ++s) {
        if (s * 512 < Lpad) {   // wave-uniform branch
            int j0 = (s << 9) + (lane << 3);
            bf16x8 h = *(const bf16x8*)&srow[j0];
#pragma unroll
            for (int e = 0; e < 8; ++e) {
                float f = ((j0 + e) < L) ? bf2f(h[e]) : -1e30f;
                vals[s * 8 + e] = f;
                mx = fmaxf(mx, f);
            }
        }
    }
#pragma unroll
    for (int o = 32; o > 0; o >>= 1) mx = fmaxf(mx, __shfl_down(mx, o));
    mx = __shfl(mx, 0);

    float sum = 0.f;
#pragma unroll
    for (int s = 0; s < 4; ++s) {
        if (s * 512 < Lpad) {
#pragma unroll
            for (int e = 0; e < 8; ++e) {
                float ex = __expf(vals[s * 8 + e] - mx);  // masked -> 0
                vals[s * 8 + e] = ex;
                sum += ex;
            }
        }
    }
#pragma unroll
    for (int o = 32; o > 0; o >>= 1) sum += __shfl_down(sum, o);
    sum = __shfl(sum, 0);
    float rinv = 1.0f / sum;

#pragma unroll
    for (int s = 0; s < 4; ++s) {
        if (s * 512 < Lpad) {
            int j0 = (s << 9) + (lane << 3);
            bf16x8 o8;
#pragma unroll
            for (int e = 0; e < 8; ++e) o8[e] = f2bf(vals[s * 8 + e] * rinv);
            *(bf16x8*)&srow[j0] = o8;
        }
    }
}

extern "C" void kernel_launch(void* const* d_in, const int* in_sizes, int n_in,
                              void* d_out, int out_size, void* d_ws, size_t ws_size,
                              hipStream_t stream) {
    const float* x  = (const float*)d_in[0];
    const float* wq = (const float*)d_in[1];
    const float* wk = (const float*)d_in[2];
    const float* wv = (const float*)d_in[3];
    float* out = (float*)d_out;

    // workspace layout (shorts)
    short* ws16 = (short*)d_ws;
    short* xb  = ws16;                 //  8,388,608
    short* wqb = xb + 8388608;         //  1,048,576
    short* wkb = wqb + 1048576;        //  1,048,576
    short* wtv = wkb + 1048576;        //  1,048,576  Wv^T [n][k]
    short* Mt  = wtv + 1048576;        //  1,048,576  (Wk Wq^T)/32
    short* tb  = Mt + 1048576;         //  8,388,608  t = x M
    short* vt  = tb + 8388608;         //  8,388,608  V^T [4][1024][2048]
    short* scores = vt + 8388608;      // 16,777,216  bf16 [4][2048][2048]

    convall<<<2048, 256, 0, stream>>>(x, wq, wk, xb, wqb, wkb);
    wtrans<<<dim3(16, 16, 1), 256, 0, stream>>>(wv, wtv);
    // Mt[m][n] = sum_e Wk[m][e] Wq[n][e] / 32
    gemm128<5><<<64, 256, 0, stream>>>(
        wkb, 1024, 0LL, wqb, 1024, 0LL, Mt, 0.03125f,
        nullptr, nullptr, nullptr);
    // t[i][n] = sum_k x[i][k] Mt[n][k]
    gemm128<5><<<512, 256, 0, stream>>>(
        xb, 1024, 0LL, Mt, 1024, 0LL, tb, 1.0f,
        nullptr, nullptr, nullptr);
    // merged: scores (544 live triangular, bf16 out) + VT (512)
    gemm128<1><<<1056, 256, 0, stream>>>(
        tb, 1024, 2097152LL, xb, 1024, 2097152LL, scores, 1.0f,
        wtv, xb, vt);
    softmax_wave<<<2048, 256, 0, stream>>>(scores);
    // out = attn @ vt^T, Kend = m0+128, paired block map; attn lda=2048
    gemm128<2><<<512, 256, 0, stream>>>(
        scores, 2048, 4194304LL, vt, 2048, 2097152LL, out, 1.0f,
        nullptr, nullptr, nullptr);
}